// Round 6
// baseline (1111.454 us; speedup 1.0000x reference)
//
#include <hip/hip_runtime.h>
#include <stdint.h>

typedef short bf8 __attribute__((ext_vector_type(8)));   // 8 bf16 (4 VGPRs)
typedef float f4  __attribute__((ext_vector_type(4)));   // MFMA acc
typedef unsigned short u16;
typedef unsigned long long u64;

struct u64x2 { u64 a, b; };   // 16B pack for bit_cast into bf8

#define LOG2E 1.4426950408889634f

__device__ __forceinline__ u16 f2bf(float f){
  uint32_t u = __builtin_bit_cast(uint32_t, f);
  u += 0x7fffu + ((u >> 16) & 1u);
  return (u16)(u >> 16);
}

// Fused LSTM cell from prescaled pre-activations.
// ai,af,ao prescaled by log2e; ag by 2*log2e; E* = 2^-a*.
// c' = c/(1+Ef) + (1-Eg)/((1+Ei)(1+Eg))   [one rcp via common denominator]
// h  = (1-Ec)/((1+Eo)(1+Ec)),  Ec = 2^(-2*log2e*c')
// 5 exp2 + 2 rcp = 7 trans ops.
__device__ __forceinline__ float lstm_cell(float ai, float af, float ag, float ao, float& c){
  float Ei = __builtin_amdgcn_exp2f(-ai);
  float Ef = __builtin_amdgcn_exp2f(-af);
  float Eg = __builtin_amdgcn_exp2f(-ag);
  float Eo = __builtin_amdgcn_exp2f(-ao);
  float m1  = (1.f + Ei) * (1.f + Eg);
  float a3  = 1.f + Ef;
  float num = fmaf(c, m1, (1.f - Eg) * a3);
  c = num * __builtin_amdgcn_rcpf(a3 * m1);
  float Ec = __builtin_amdgcn_exp2f(c * (-2.f * LOG2E));
  return (1.f - Ec) * __builtin_amdgcn_rcpf((1.f + Eo) * (1.f + Ec));
}

// ---------------------------------------------------------------------------
// Prep: prescaled bf16 weights W0c[512][160]=[Whh0|Wih0|0], W1c[512][256]=
// [Whh1|Wih1]; rows scaled log2e (i,f,o) / 2*log2e (g); prescaled biases;
// zero the progress counters (ws is poisoned 0xAA before every launch!).
// ---------------------------------------------------------------------------
__global__ void prep_kernel(const float* __restrict__ Wih0, const float* __restrict__ Whh0,
                            const float* __restrict__ bih0, const float* __restrict__ bhh0,
                            const float* __restrict__ Wih1, const float* __restrict__ Whh1,
                            const float* __restrict__ bih1, const float* __restrict__ bhh1,
                            u16* __restrict__ W0c, u16* __restrict__ W1c,
                            float* __restrict__ bias0, float* __restrict__ bias1,
                            int* __restrict__ prog){
  int g = blockIdx.x;      // gate row 0..511
  int t = threadIdx.x;     // 0..63
  float s = (g >= 256 && g < 384) ? 2.0f * LOG2E : LOG2E;
  for(int k = t; k < 160; k += 64){
    float v = 0.0f;
    if(k < 128)      v = Whh0[g*128 + k];
    else if(k < 146) v = Wih0[g*18 + (k-128)];
    W0c[g*160 + k] = f2bf(v * s);
  }
  for(int k = t; k < 256; k += 64){
    float v = (k < 128) ? Whh1[g*128 + k] : Wih1[g*128 + (k-128)];
    W1c[g*256 + k] = f2bf(v * s);
  }
  if(t == 0){
    bias0[g] = (bih0[g] + bhh0[g]) * s;
    bias1[g] = (bih1[g] + bhh1[g]) * s;
  }
  if(g == 0 && t < 32) prog[t] = 0;
}

// ---------------------------------------------------------------------------
// Fused 2-layer LSTM. 64 blocks x 512 threads; bid<32: L0 role, else L1.
// R6 = EXACT R2 base (563us champion; R3/R4/R5 deltas reverted) + ONE change:
//  * L1's LDS h1 ring ELIMINATED. Each wave loads its own h1 B-fragments
//    straight from h1g into registers (8 u64 agent loads/step, same sc0/L2
//    path the ring staging used -> bit-identical data), double-buffered in
//    statically-named Fa/Fb, issued 1 step ahead (~1100cyc slack > 900cyc
//    worst-case latency). Rationale: lockstep makes the per-CU LDS pipe the
//    burstiest term (~960cyc/step on L1: 8 waves x 10 ops x ~12cyc); this
//    removes 5 of 10 LDS ops/wave, shifting them to the near-idle vmem pipe.
// ---------------------------------------------------------------------------
__global__ __launch_bounds__(512, 1)
void lstm_fused(const u16* __restrict__ Wc0, const u16* __restrict__ Wc1,
                const float* __restrict__ bias0, const float* __restrict__ bias1,
                const float* __restrict__ xin,   // (512,512,18) f32
                u64* __restrict__ h1g,           // [T][512 rows][32 u64] bf16x4
                int* __restrict__ prog,          // [32] per-rowblock progress
                const float* __restrict__ Wfc1, const float* __restrict__ bfc1,
                const float* __restrict__ Wfc2, const float* __restrict__ bfc2,
                float* __restrict__ out)         // (512,) f32
{
  __shared__ __align__(16) u16  hb[2][16][136];   // L0 h-state (cols 0..127)
  __shared__ __align__(16) u16  xb[2][16][40];    // L0 x tiles (cols 18..31 stay 0)
  __shared__ __align__(16) u16  h2b[2][16][136];  // L1 h2 state
  __shared__ __align__(16) float ffin[16][132];   // final h2 f32 for FC head

  const int tid  = threadIdx.x;
  const int wave = tid >> 6;
  const int lane = tid & 63;
  const int quad = lane >> 4;
  const int l15  = lane & 15;
  const bool isL0 = (blockIdx.x < 32);
  const int rb   = isL0 ? blockIdx.x : (blockIdx.x - 32);
  const int rowbase = rb * 16;

  if(isL0){
    // ------------- L0: h-part K=128 (kt0..3) + x-part K=32 (own tile) -----
    bf8 Ah[4][4], Ax[4];
#pragma unroll
    for(int q = 0; q < 4; q++){
      const u16* wp = Wc0 + (u64)(128*q + 16*wave + l15)*160 + quad*8;
#pragma unroll
      for(int kt = 0; kt < 4; kt++) Ah[q][kt] = *(const bf8*)(wp + kt*32);
      Ax[q] = *(const bf8*)(wp + 128);
    }
    f4 bini[4];
#pragma unroll
    for(int q = 0; q < 4; q++) bini[q] = *(const f4*)(bias0 + 128*q + 16*wave + quad*4);
    float c[4] = {0.f,0.f,0.f,0.f};

    for(int i = tid; i < 2*16*136; i += 512) ((u16*)hb)[i] = 0;
    for(int i = tid; i < 2*16*40;  i += 512) ((u16*)xb)[i] = 0;
    __syncthreads();

    int sr = 0, sk = 0;
    if(tid < 288){
      sr = tid/18; sk = tid - 18*sr;
      xb[0][sr][sk] = f2bf(xin[((u64)(rowbase+sr)*512 + 0)*18 + sk]);
      xb[1][sr][sk] = f2bf(xin[((u64)(rowbase+sr)*512 + 1)*18 + sk]);
    }
    float xv = 0.f;
    if(tid < 288) xv = xin[((u64)(rowbase+sr)*512 + 2)*18 + sk];
    __syncthreads();

    f4 pre[4];
    {
      bf8 Bx = *(const bf8*)(&xb[0][l15][quad*8]);
#pragma unroll
      for(int q = 0; q < 4; q++)
        pre[q] = __builtin_amdgcn_mfma_f32_16x16x32_bf16(Ax[q], Bx, bini[q], 0,0,0);
    }
    __syncthreads();   // xb[0] gets overwritten at t=0

    for(int t = 0; t < 512; t++){
      const int cur = t & 1, nxt = cur ^ 1;
      // stage x(t+2) from reg; issue load of x(t+3) (uniform vmem count)
      if(tid < 288){
        if(t <= 509) xb[t & 1][sr][sk] = f2bf(xv);
        const int tl = (t + 3 < 512) ? t + 3 : 511;
        xv = xin[((u64)(rowbase+sr)*512 + tl)*18 + sk];
      }

      bf8 B[4];
      const u16* br = &hb[cur][l15][quad*8];
#pragma unroll
      for(int kt = 0; kt < 4; kt++) B[kt] = *(const bf8*)(br + kt*32);

      f4 acc[4];
#pragma unroll
      for(int q = 0; q < 4; q++){
        f4 a = pre[q];
#pragma unroll
        for(int kt = 0; kt < 4; kt++)
          a = __builtin_amdgcn_mfma_f32_16x16x32_bf16(Ah[q][kt], B[kt], a, 0,0,0);
        acc[q] = a;
      }

      u64 hpack; u16* hp = (u16*)&hpack;
#pragma unroll
      for(int r = 0; r < 4; r++)
        hp[r] = f2bf(lstm_cell(acc[0][r], acc[1][r], acc[2][r], acc[3][r], c[r]));

      *(u64*)(&hb[nxt][l15][16*wave + quad*4]) = hpack;
      __hip_atomic_store(h1g + ((u64)t*512 + rowbase + l15)*32 + 4*wave + quad,
                         hpack, __ATOMIC_RELAXED, __HIP_MEMORY_SCOPE_AGENT);

      // precompute x-part for step t+1 (off the dependent chain)
      if(t < 511){
        bf8 Bxn = *(const bf8*)(&xb[(t+1) & 1][l15][quad*8]);
#pragma unroll
        for(int q = 0; q < 4; q++)
          pre[q] = __builtin_amdgcn_mfma_f32_16x16x32_bf16(Ax[q], Bxn, bini[q], 0,0,0);
      }

      // counted-vmcnt barrier. Per step, waves 0-4 issue [xload, h1store],
      // waves 5-7 [h1store]. vmcnt(4)/(2) ==> store(t-2) retired (in-order),
      // so publishing prog = t-1 is completion-safe with a relaxed store.
      __builtin_amdgcn_sched_barrier(0);
      if(wave < 5) asm volatile("s_waitcnt vmcnt(4) lgkmcnt(0)" ::: "memory");
      else         asm volatile("s_waitcnt vmcnt(2) lgkmcnt(0)" ::: "memory");
      __builtin_amdgcn_s_barrier();
      __builtin_amdgcn_sched_barrier(0);
      if(tid == 0 && t > 0)
        __hip_atomic_store(prog + rb, t - 1, __ATOMIC_RELAXED, __HIP_MEMORY_SCOPE_AGENT);
    }
    asm volatile("s_waitcnt vmcnt(0)" ::: "memory");
    __builtin_amdgcn_s_barrier();
    if(tid == 0)
      __hip_atomic_store(prog + rb, 512, __ATOMIC_RELAXED, __HIP_MEMORY_SCOPE_AGENT);
  } else {
    // ------------- L1: h2-part K=128 (chain) + h1-part K=128 (pre) --------
    // h1 operand comes straight from h1g into registers (no LDS ring).
    bf8 A2[4][4], A1[4][4];
#pragma unroll
    for(int q = 0; q < 4; q++){
      const u16* wp = Wc1 + (u64)(128*q + 16*wave + l15)*256 + quad*8;
#pragma unroll
      for(int kt = 0; kt < 4; kt++){
        A2[q][kt] = *(const bf8*)(wp + kt*32);
        A1[q][kt] = *(const bf8*)(wp + 128 + kt*32);
      }
    }
    f4 bini[4];
#pragma unroll
    for(int q = 0; q < 4; q++) bini[q] = *(const f4*)(bias1 + 128*q + 16*wave + quad*4);
    float c[4] = {0.f,0.f,0.f,0.f};

    for(int i = tid; i < 2*16*136; i += 512) ((u16*)h2b)[i] = 0;

    int seen = 0;
    __syncthreads();

    // per-lane fragment base pattern: row rowbase+l15, u64s quad*2 + kt*8 (+1)
    // (bit-identical to the old ring path: ring[s][pr][pu*4] <- h1g[.. pr*32+pu])
    // prologue: need h1(0),h1(1) => seen >= 2
    while(seen < 2){
      seen = __hip_atomic_load(prog + rb, __ATOMIC_ACQUIRE, __HIP_MEMORY_SCOPE_AGENT);
      if(seen < 2) __builtin_amdgcn_s_sleep(2);
    }
    f4 pre[4];
    bf8 Fa[4], Fb[4];
    {
      const u64* gp0 = h1g + ((u64)0*512 + rowbase + l15)*32 + quad*2;
      bf8 T0[4];
#pragma unroll
      for(int kt = 0; kt < 4; kt++){
        u64 lo = __hip_atomic_load(gp0 + kt*8,     __ATOMIC_RELAXED, __HIP_MEMORY_SCOPE_AGENT);
        u64 hi = __hip_atomic_load(gp0 + kt*8 + 1, __ATOMIC_RELAXED, __HIP_MEMORY_SCOPE_AGENT);
        u64x2 u{lo, hi};
        T0[kt] = __builtin_bit_cast(bf8, u);
      }
#pragma unroll
      for(int q = 0; q < 4; q++){
        f4 a = bini[q];
#pragma unroll
        for(int kt = 0; kt < 4; kt++)
          a = __builtin_amdgcn_mfma_f32_16x16x32_bf16(A1[q][kt], T0[kt], a, 0,0,0);
        pre[q] = a;
      }
      const u64* gp1 = h1g + ((u64)1*512 + rowbase + l15)*32 + quad*2;
#pragma unroll
      for(int kt = 0; kt < 4; kt++){
        u64 lo = __hip_atomic_load(gp1 + kt*8,     __ATOMIC_RELAXED, __HIP_MEMORY_SCOPE_AGENT);
        u64 hi = __hip_atomic_load(gp1 + kt*8 + 1, __ATOMIC_RELAXED, __HIP_MEMORY_SCOPE_AGENT);
        u64x2 u{lo, hi};
        Fa[kt] = __builtin_bit_cast(bf8, u);
      }
    }

    float hv[4] = {0.f,0.f,0.f,0.f};

    // STEP(t): entry invariant: BCUR holds h1(t+1); issues BNEXT <- h1(t+2).
    // Statically-named Fa/Fb (rule: runtime-indexed reg arrays spill).
#define L1_STEP(T, BCUR, BNEXT)                                                          \
    do{                                                                                  \
      const int cur_ = (T) & 1, nxt_ = cur_ ^ 1;                                         \
      if((T) <= 509){                                                                    \
        const int need_ = (T) + 3;                                                       \
        while(seen < need_){                                                             \
          seen = __hip_atomic_load(prog + rb, __ATOMIC_ACQUIRE, __HIP_MEMORY_SCOPE_AGENT); \
          if(seen < need_) __builtin_amdgcn_s_sleep(2);                                  \
        }                                                                                \
        const u64* gp_ = h1g + ((u64)((T)+2)*512 + rowbase + l15)*32 + quad*2;           \
        _Pragma("unroll")                                                                \
        for(int kt = 0; kt < 4; kt++){                                                   \
          u64 lo_ = __hip_atomic_load(gp_ + kt*8,     __ATOMIC_RELAXED, __HIP_MEMORY_SCOPE_AGENT); \
          u64 hi_ = __hip_atomic_load(gp_ + kt*8 + 1, __ATOMIC_RELAXED, __HIP_MEMORY_SCOPE_AGENT); \
          u64x2 u_{lo_, hi_};                                                            \
          BNEXT[kt] = __builtin_bit_cast(bf8, u_);                                       \
        }                                                                                \
      }                                                                                  \
      bf8 B2_[4];                                                                        \
      const u16* br2_ = &h2b[cur_][l15][quad*8];                                         \
      _Pragma("unroll")                                                                  \
      for(int kt = 0; kt < 4; kt++) B2_[kt] = *(const bf8*)(br2_ + kt*32);               \
      f4 acc_[4];                                                                        \
      _Pragma("unroll")                                                                  \
      for(int q = 0; q < 4; q++){                                                        \
        f4 a_ = pre[q];                                                                  \
        _Pragma("unroll")                                                                \
        for(int kt = 0; kt < 4; kt++)                                                    \
          a_ = __builtin_amdgcn_mfma_f32_16x16x32_bf16(A2[q][kt], B2_[kt], a_, 0,0,0);   \
        acc_[q] = a_;                                                                    \
      }                                                                                  \
      if((T) < 511){                                                                     \
        _Pragma("unroll")                                                                \
        for(int q = 0; q < 4; q++){                                                      \
          f4 a_ = bini[q];                                                               \
          _Pragma("unroll")                                                              \
          for(int kt = 0; kt < 4; kt++)                                                  \
            a_ = __builtin_amdgcn_mfma_f32_16x16x32_bf16(A1[q][kt], BCUR[kt], a_, 0,0,0);\
          pre[q] = a_;                                                                   \
        }                                                                                \
      }                                                                                  \
      u64 hpack_; u16* hp_ = (u16*)&hpack_;                                              \
      _Pragma("unroll")                                                                  \
      for(int r = 0; r < 4; r++){                                                        \
        hv[r] = lstm_cell(acc_[0][r], acc_[1][r], acc_[2][r], acc_[3][r], c[r]);         \
        hp_[r] = f2bf(hv[r]);                                                            \
      }                                                                                  \
      *(u64*)(&h2b[nxt_][l15][16*wave + quad*4]) = hpack_;                               \
      __builtin_amdgcn_sched_barrier(0);                                                 \
      asm volatile("s_waitcnt lgkmcnt(0)" ::: "memory");                                 \
      __builtin_amdgcn_s_barrier();                                                      \
      __builtin_amdgcn_sched_barrier(0);                                                 \
    }while(0)

    for(int tt = 0; tt < 512; tt += 2){
      L1_STEP(tt,     Fa, Fb);
      L1_STEP(tt + 1, Fb, Fa);
    }
#undef L1_STEP

    // stash final h2 (f32) for FC head
#pragma unroll
    for(int r = 0; r < 4; r++) ffin[l15][16*wave + quad*4 + r] = hv[r];
    __syncthreads();

    // ---- FC head: per row r, 64 hidden, 32 threads x 2v each
    {
      int r = tid >> 5, u = tid & 31;
      float s0 = bfc1[2*u], s1 = bfc1[2*u+1];
      const float* w0 = Wfc1 + (2*u)*128;
      const float* w1 = Wfc1 + (2*u+1)*128;
      for(int j = 0; j < 128; j++){
        float h = ffin[r][j];
        s0 = fmaf(w0[j], h, s0);
        s1 = fmaf(w1[j], h, s1);
      }
      float term = fmaxf(s0, 0.f)*Wfc2[2*u] + fmaxf(s1, 0.f)*Wfc2[2*u+1];
#pragma unroll
      for(int off = 16; off > 0; off >>= 1) term += __shfl_down(term, off, 32);
      if(u == 0){
        float z = (term + bfc2[0]) * LOG2E;
        out[rowbase + r] = __builtin_amdgcn_rcpf(1.0f + __builtin_amdgcn_exp2f(-z));
      }
    }
  }
}

// ---------------------------------------------------------------------------
extern "C" void kernel_launch(void* const* d_in, const int* in_sizes, int n_in,
                              void* d_out, int out_size, void* d_ws, size_t ws_size,
                              hipStream_t stream){
  const float* x    = (const float*)d_in[0];
  const float* Wih0 = (const float*)d_in[1];
  const float* Whh0 = (const float*)d_in[2];
  const float* bih0 = (const float*)d_in[3];
  const float* bhh0 = (const float*)d_in[4];
  const float* Wih1 = (const float*)d_in[5];
  const float* Whh1 = (const float*)d_in[6];
  const float* bih1 = (const float*)d_in[7];
  const float* bhh1 = (const float*)d_in[8];
  const float* Wfc1 = (const float*)d_in[9];
  const float* bfc1 = (const float*)d_in[10];
  const float* Wfc2 = (const float*)d_in[11];
  const float* bfc2 = (const float*)d_in[12];

  char* ws = (char*)d_ws;
  u16*   W0c   = (u16*)(ws);                       // 512*160*2 = 163840 B
  u16*   W1c   = (u16*)(ws + 163840);              // 512*256*2 = 262144 B
  float* bias0 = (float*)(ws + 163840 + 262144);   // 2048 B
  float* bias1 = bias0 + 512;                      // 2048 B
  int*   prog  = (int*)(ws + 163840 + 262144 + 4096);  // 128 B (pad to 256)
  u64*   h1g   = (u64*)(ws + 163840 + 262144 + 4096 + 256); // 64 MiB

  prep_kernel<<<dim3(512), dim3(64), 0, stream>>>(Wih0, Whh0, bih0, bhh0,
                                                  Wih1, Whh1, bih1, bhh1,
                                                  W0c, W1c, bias0, bias1, prog);

  lstm_fused<<<dim3(64), dim3(512), 0, stream>>>(
      W0c, W1c, bias0, bias1, x, h1g, prog,
      Wfc1, bfc1, Wfc2, bfc2, (float*)d_out);
}

// Round 7
// 723.630 us; speedup vs baseline: 1.5359x; 1.5359x over previous
//
#include <hip/hip_runtime.h>
#include <stdint.h>

typedef short bf8 __attribute__((ext_vector_type(8)));   // 8 bf16 (4 VGPRs)
typedef float f4  __attribute__((ext_vector_type(4)));   // MFMA acc
typedef unsigned short u16;
typedef unsigned long long u64;

#define LOG2E 1.4426950408889634f

__device__ __forceinline__ u16 f2bf(float f){
  uint32_t u = __builtin_bit_cast(uint32_t, f);
  u += 0x7fffu + ((u >> 16) & 1u);
  return (u16)(u >> 16);
}

// Fused LSTM cell from prescaled pre-activations.
// ai,af,ao prescaled by log2e; ag by 2*log2e; E* = 2^-a*.
// c' = c/(1+Ef) + (1-Eg)/((1+Ei)(1+Eg))   [one rcp via common denominator]
// h  = (1-Ec)/((1+Eo)(1+Ec)),  Ec = 2^(-2*log2e*c')
// 5 exp2 + 2 rcp = 7 trans ops.
__device__ __forceinline__ float lstm_cell(float ai, float af, float ag, float ao, float& c){
  float Ei = __builtin_amdgcn_exp2f(-ai);
  float Ef = __builtin_amdgcn_exp2f(-af);
  float Eg = __builtin_amdgcn_exp2f(-ag);
  float Eo = __builtin_amdgcn_exp2f(-ao);
  float m1  = (1.f + Ei) * (1.f + Eg);
  float a3  = 1.f + Ef;
  float num = fmaf(c, m1, (1.f - Eg) * a3);
  c = num * __builtin_amdgcn_rcpf(a3 * m1);
  float Ec = __builtin_amdgcn_exp2f(c * (-2.f * LOG2E));
  return (1.f - Ec) * __builtin_amdgcn_rcpf((1.f + Eo) * (1.f + Ec));
}

// ---------------------------------------------------------------------------
// Prep: prescaled bf16 weights W0c[512][160]=[Whh0|Wih0|0], W1c[512][256]=
// [Whh1|Wih1]; rows scaled log2e (i,f,o) / 2*log2e (g); prescaled biases;
// zero the progress counters (ws is poisoned 0xAA before every launch!).
// ---------------------------------------------------------------------------
__global__ void prep_kernel(const float* __restrict__ Wih0, const float* __restrict__ Whh0,
                            const float* __restrict__ bih0, const float* __restrict__ bhh0,
                            const float* __restrict__ Wih1, const float* __restrict__ Whh1,
                            const float* __restrict__ bih1, const float* __restrict__ bhh1,
                            u16* __restrict__ W0c, u16* __restrict__ W1c,
                            float* __restrict__ bias0, float* __restrict__ bias1,
                            int* __restrict__ prog){
  int g = blockIdx.x;      // gate row 0..511
  int t = threadIdx.x;     // 0..63
  float s = (g >= 256 && g < 384) ? 2.0f * LOG2E : LOG2E;
  for(int k = t; k < 160; k += 64){
    float v = 0.0f;
    if(k < 128)      v = Whh0[g*128 + k];
    else if(k < 146) v = Wih0[g*18 + (k-128)];
    W0c[g*160 + k] = f2bf(v * s);
  }
  for(int k = t; k < 256; k += 64){
    float v = (k < 128) ? Whh1[g*128 + k] : Wih1[g*128 + (k-128)];
    W1c[g*256 + k] = f2bf(v * s);
  }
  if(t == 0){
    bias0[g] = (bih0[g] + bhh0[g]) * s;
    bias1[g] = (bih1[g] + bhh1[g]) * s;
  }
  if(g == 0 && t < 32) prog[t] = 0;
}

// ---------------------------------------------------------------------------
// Fused 2-layer LSTM. 64 blocks x 512 threads; bid<32: L0 role, else L1.
// R7 = EXACT R2 base (563us champion; R3-R6 structural probes all reverted —
// each was neutral-to-negative: occupancy attrs, skew balance, MFMA split,
// register-direct h1 gather). Single zero-risk reorder vs R2:
//  * L1's poll+prefetch block moved AFTER the pre-MFMA computation so a rare
//    poll-miss (cross-XCD atomic ~700cyc) can never insert itself ahead of
//    the step's dependent MFMA chain. Numerics and schedule otherwise
//    byte-identical to R2.
// ---------------------------------------------------------------------------
__global__ __launch_bounds__(512, 1)
void lstm_fused(const u16* __restrict__ Wc0, const u16* __restrict__ Wc1,
                const float* __restrict__ bias0, const float* __restrict__ bias1,
                const float* __restrict__ xin,   // (512,512,18) f32
                u64* __restrict__ h1g,           // [T][512 rows][32 u64] bf16x4
                int* __restrict__ prog,          // [32] per-rowblock progress
                const float* __restrict__ Wfc1, const float* __restrict__ bfc1,
                const float* __restrict__ Wfc2, const float* __restrict__ bfc2,
                float* __restrict__ out)         // (512,) f32
{
  __shared__ __align__(16) u16  hb[2][16][136];   // L0 h-state (cols 0..127)
  __shared__ __align__(16) u16  xb[2][16][40];    // L0 x tiles (cols 18..31 stay 0)
  __shared__ __align__(16) u16  h2b[2][16][136];  // L1 h2 state
  __shared__ __align__(16) u16  ring[4][16][136]; // L1 h1 ring
  __shared__ __align__(16) float ffin[16][132];   // final h2 f32 for FC head

  const int tid  = threadIdx.x;
  const int wave = tid >> 6;
  const int lane = tid & 63;
  const int quad = lane >> 4;
  const int l15  = lane & 15;
  const bool isL0 = (blockIdx.x < 32);
  const int rb   = isL0 ? blockIdx.x : (blockIdx.x - 32);
  const int rowbase = rb * 16;

  if(isL0){
    // ------------- L0: h-part K=128 (kt0..3) + x-part K=32 (own tile) -----
    bf8 Ah[4][4], Ax[4];
#pragma unroll
    for(int q = 0; q < 4; q++){
      const u16* wp = Wc0 + (u64)(128*q + 16*wave + l15)*160 + quad*8;
#pragma unroll
      for(int kt = 0; kt < 4; kt++) Ah[q][kt] = *(const bf8*)(wp + kt*32);
      Ax[q] = *(const bf8*)(wp + 128);
    }
    f4 bini[4];
#pragma unroll
    for(int q = 0; q < 4; q++) bini[q] = *(const f4*)(bias0 + 128*q + 16*wave + quad*4);
    float c[4] = {0.f,0.f,0.f,0.f};

    for(int i = tid; i < 2*16*136; i += 512) ((u16*)hb)[i] = 0;
    for(int i = tid; i < 2*16*40;  i += 512) ((u16*)xb)[i] = 0;
    __syncthreads();

    int sr = 0, sk = 0;
    if(tid < 288){
      sr = tid/18; sk = tid - 18*sr;
      xb[0][sr][sk] = f2bf(xin[((u64)(rowbase+sr)*512 + 0)*18 + sk]);
      xb[1][sr][sk] = f2bf(xin[((u64)(rowbase+sr)*512 + 1)*18 + sk]);
    }
    float xv = 0.f;
    if(tid < 288) xv = xin[((u64)(rowbase+sr)*512 + 2)*18 + sk];
    __syncthreads();

    f4 pre[4];
    {
      bf8 Bx = *(const bf8*)(&xb[0][l15][quad*8]);
#pragma unroll
      for(int q = 0; q < 4; q++)
        pre[q] = __builtin_amdgcn_mfma_f32_16x16x32_bf16(Ax[q], Bx, bini[q], 0,0,0);
    }
    __syncthreads();   // xb[0] gets overwritten at t=0

    for(int t = 0; t < 512; t++){
      const int cur = t & 1, nxt = cur ^ 1;
      // stage x(t+2) from reg; issue load of x(t+3) (uniform vmem count)
      if(tid < 288){
        if(t <= 509) xb[t & 1][sr][sk] = f2bf(xv);
        const int tl = (t + 3 < 512) ? t + 3 : 511;
        xv = xin[((u64)(rowbase+sr)*512 + tl)*18 + sk];
      }

      bf8 B[4];
      const u16* br = &hb[cur][l15][quad*8];
#pragma unroll
      for(int kt = 0; kt < 4; kt++) B[kt] = *(const bf8*)(br + kt*32);

      f4 acc[4];
#pragma unroll
      for(int q = 0; q < 4; q++){
        f4 a = pre[q];
#pragma unroll
        for(int kt = 0; kt < 4; kt++)
          a = __builtin_amdgcn_mfma_f32_16x16x32_bf16(Ah[q][kt], B[kt], a, 0,0,0);
        acc[q] = a;
      }

      u64 hpack; u16* hp = (u16*)&hpack;
#pragma unroll
      for(int r = 0; r < 4; r++)
        hp[r] = f2bf(lstm_cell(acc[0][r], acc[1][r], acc[2][r], acc[3][r], c[r]));

      *(u64*)(&hb[nxt][l15][16*wave + quad*4]) = hpack;
      __hip_atomic_store(h1g + ((u64)t*512 + rowbase + l15)*32 + 4*wave + quad,
                         hpack, __ATOMIC_RELAXED, __HIP_MEMORY_SCOPE_AGENT);

      // precompute x-part for step t+1 (off the dependent chain)
      if(t < 511){
        bf8 Bxn = *(const bf8*)(&xb[(t+1) & 1][l15][quad*8]);
#pragma unroll
        for(int q = 0; q < 4; q++)
          pre[q] = __builtin_amdgcn_mfma_f32_16x16x32_bf16(Ax[q], Bxn, bini[q], 0,0,0);
      }

      // counted-vmcnt barrier. Per step, waves 0-4 issue [xload, h1store],
      // waves 5-7 [h1store]. vmcnt(4)/(2) ==> store(t-2) retired (in-order),
      // so publishing prog = t-1 is completion-safe with a relaxed store.
      __builtin_amdgcn_sched_barrier(0);
      if(wave < 5) asm volatile("s_waitcnt vmcnt(4) lgkmcnt(0)" ::: "memory");
      else         asm volatile("s_waitcnt vmcnt(2) lgkmcnt(0)" ::: "memory");
      __builtin_amdgcn_s_barrier();
      __builtin_amdgcn_sched_barrier(0);
      if(tid == 0 && t > 0)
        __hip_atomic_store(prog + rb, t - 1, __ATOMIC_RELAXED, __HIP_MEMORY_SCOPE_AGENT);
    }
    asm volatile("s_waitcnt vmcnt(0)" ::: "memory");
    __builtin_amdgcn_s_barrier();
    if(tid == 0)
      __hip_atomic_store(prog + rb, 512, __ATOMIC_RELAXED, __HIP_MEMORY_SCOPE_AGENT);
  } else {
    // ------------- L1: h2-part K=128 (chain) + h1-part K=128 (pre) --------
    bf8 A2[4][4], A1[4][4];
#pragma unroll
    for(int q = 0; q < 4; q++){
      const u16* wp = Wc1 + (u64)(128*q + 16*wave + l15)*256 + quad*8;
#pragma unroll
      for(int kt = 0; kt < 4; kt++){
        A2[q][kt] = *(const bf8*)(wp + kt*32);
        A1[q][kt] = *(const bf8*)(wp + 128 + kt*32);
      }
    }
    f4 bini[4];
#pragma unroll
    for(int q = 0; q < 4; q++) bini[q] = *(const f4*)(bias1 + 128*q + 16*wave + quad*4);
    float c[4] = {0.f,0.f,0.f,0.f};

    for(int i = tid; i < 2*16*136; i += 512) ((u16*)h2b)[i] = 0;

    const int pr = tid >> 5;          // staging row 0..15
    const int pu = tid & 31;          // staging u64-chunk (4 comps)
    int seen = 0;
    __syncthreads();

    // prologue: stage h1(0)->ring0, h1(1)->ring1; preload pv=h1(2)
    while(seen < 2){
      seen = __hip_atomic_load(prog + rb, __ATOMIC_ACQUIRE, __HIP_MEMORY_SCOPE_AGENT);
      if(seen < 2) __builtin_amdgcn_s_sleep(2);
    }
    {
      u64 v0 = __hip_atomic_load(h1g + ((u64)0*512 + rowbase + pr)*32 + pu,
                                 __ATOMIC_RELAXED, __HIP_MEMORY_SCOPE_AGENT);
      *(u64*)(&ring[0][pr][pu*4]) = v0;
      u64 v1 = __hip_atomic_load(h1g + ((u64)1*512 + rowbase + pr)*32 + pu,
                                 __ATOMIC_RELAXED, __HIP_MEMORY_SCOPE_AGENT);
      *(u64*)(&ring[1][pr][pu*4]) = v1;
    }
    while(seen < 3){
      seen = __hip_atomic_load(prog + rb, __ATOMIC_ACQUIRE, __HIP_MEMORY_SCOPE_AGENT);
      if(seen < 3) __builtin_amdgcn_s_sleep(2);
    }
    u64 pv = __hip_atomic_load(h1g + ((u64)2*512 + rowbase + pr)*32 + pu,
                               __ATOMIC_RELAXED, __HIP_MEMORY_SCOPE_AGENT);
    __syncthreads();

    f4 pre[4];
    {
      const u16* rr = &ring[0][l15][quad*8];
#pragma unroll
      for(int q = 0; q < 4; q++){
        f4 a = bini[q];
#pragma unroll
        for(int kt = 0; kt < 4; kt++)
          a = __builtin_amdgcn_mfma_f32_16x16x32_bf16(A1[q][kt], *(const bf8*)(rr + kt*32), a, 0,0,0);
        pre[q] = a;
      }
    }

    float hv[4] = {0.f,0.f,0.f,0.f};
    for(int t = 0; t < 512; t++){
      const int cur = t & 1, nxt = cur ^ 1;

      bf8 B2[4];
      const u16* br2 = &h2b[cur][l15][quad*8];
#pragma unroll
      for(int kt = 0; kt < 4; kt++) B2[kt] = *(const bf8*)(br2 + kt*32);

      // 4-deep chain seeded with pre (h1(t) contribution + bias)
      f4 acc[4];
#pragma unroll
      for(int q = 0; q < 4; q++){
        f4 a = pre[q];
#pragma unroll
        for(int kt = 0; kt < 4; kt++)
          a = __builtin_amdgcn_mfma_f32_16x16x32_bf16(A2[q][kt], B2[kt], a, 0,0,0);
        acc[q] = a;
      }

      // precompute h1(t+1) contribution for next step (off-chain)
      if(t < 511){
        const u16* rr = &ring[(t+1) & 3][l15][quad*8];
#pragma unroll
        for(int q = 0; q < 4; q++){
          f4 a = bini[q];
#pragma unroll
          for(int kt = 0; kt < 4; kt++)
            a = __builtin_amdgcn_mfma_f32_16x16x32_bf16(A1[q][kt], *(const bf8*)(rr + kt*32), a, 0,0,0);
          pre[q] = a;
        }
      }

      // amortized poll + prefetch h1(t+3) — placed AFTER the dependent
      // chains so a poll-miss can never extend the critical path.
      u64 pnew = 0;
      if(t <= 508){
        const int need = t + 4;
        while(seen < need){
          seen = __hip_atomic_load(prog + rb, __ATOMIC_ACQUIRE, __HIP_MEMORY_SCOPE_AGENT);
          if(seen < need) __builtin_amdgcn_s_sleep(2);
        }
        pnew = __hip_atomic_load(h1g + ((u64)(t+3)*512 + rowbase + pr)*32 + pu,
                                 __ATOMIC_RELAXED, __HIP_MEMORY_SCOPE_AGENT);
      }

      // stage h1(t+2) (loaded last step) into its ring slot
      if(t <= 509) *(u64*)(&ring[(t+2) & 3][pr][pu*4]) = pv;

      u64 hpack; u16* hp = (u16*)&hpack;
#pragma unroll
      for(int r = 0; r < 4; r++){
        hv[r] = lstm_cell(acc[0][r], acc[1][r], acc[2][r], acc[3][r], c[r]);
        hp[r] = f2bf(hv[r]);
      }
      *(u64*)(&h2b[nxt][l15][16*wave + quad*4]) = hpack;

      __builtin_amdgcn_sched_barrier(0);
      asm volatile("s_waitcnt lgkmcnt(0)" ::: "memory");
      __builtin_amdgcn_s_barrier();
      __builtin_amdgcn_sched_barrier(0);

      pv = pnew;
    }
    // stash final h2 (f32) for FC head
#pragma unroll
    for(int r = 0; r < 4; r++) ffin[l15][16*wave + quad*4 + r] = hv[r];
    __syncthreads();

    // ---- FC head: per row r, 64 hidden, 32 threads x 2v each
    {
      int r = tid >> 5, u = tid & 31;
      float s0 = bfc1[2*u], s1 = bfc1[2*u+1];
      const float* w0 = Wfc1 + (2*u)*128;
      const float* w1 = Wfc1 + (2*u+1)*128;
      for(int j = 0; j < 128; j++){
        float h = ffin[r][j];
        s0 = fmaf(w0[j], h, s0);
        s1 = fmaf(w1[j], h, s1);
      }
      float term = fmaxf(s0, 0.f)*Wfc2[2*u] + fmaxf(s1, 0.f)*Wfc2[2*u+1];
#pragma unroll
      for(int off = 16; off > 0; off >>= 1) term += __shfl_down(term, off, 32);
      if(u == 0){
        float z = (term + bfc2[0]) * LOG2E;
        out[rowbase + r] = __builtin_amdgcn_rcpf(1.0f + __builtin_amdgcn_exp2f(-z));
      }
    }
  }
}

// ---------------------------------------------------------------------------
extern "C" void kernel_launch(void* const* d_in, const int* in_sizes, int n_in,
                              void* d_out, int out_size, void* d_ws, size_t ws_size,
                              hipStream_t stream){
  const float* x    = (const float*)d_in[0];
  const float* Wih0 = (const float*)d_in[1];
  const float* Whh0 = (const float*)d_in[2];
  const float* bih0 = (const float*)d_in[3];
  const float* bhh0 = (const float*)d_in[4];
  const float* Wih1 = (const float*)d_in[5];
  const float* Whh1 = (const float*)d_in[6];
  const float* bih1 = (const float*)d_in[7];
  const float* bhh1 = (const float*)d_in[8];
  const float* Wfc1 = (const float*)d_in[9];
  const float* bfc1 = (const float*)d_in[10];
  const float* Wfc2 = (const float*)d_in[11];
  const float* bfc2 = (const float*)d_in[12];

  char* ws = (char*)d_ws;
  u16*   W0c   = (u16*)(ws);                       // 512*160*2 = 163840 B
  u16*   W1c   = (u16*)(ws + 163840);              // 512*256*2 = 262144 B
  float* bias0 = (float*)(ws + 163840 + 262144);   // 2048 B
  float* bias1 = bias0 + 512;                      // 2048 B
  int*   prog  = (int*)(ws + 163840 + 262144 + 4096);  // 128 B (pad to 256)
  u64*   h1g   = (u64*)(ws + 163840 + 262144 + 4096 + 256); // 64 MiB

  prep_kernel<<<dim3(512), dim3(64), 0, stream>>>(Wih0, Whh0, bih0, bhh0,
                                                  Wih1, Whh1, bih1, bhh1,
                                                  W0c, W1c, bias0, bias1, prog);

  lstm_fused<<<dim3(64), dim3(512), 0, stream>>>(
      W0c, W1c, bias0, bias1, x, h1g, prog,
      Wfc1, bfc1, Wfc2, bfc2, (float*)d_out);
}

// Round 8
// 631.867 us; speedup vs baseline: 1.7590x; 1.1452x over previous
//
#include <hip/hip_runtime.h>
#include <stdint.h>

typedef short bf8 __attribute__((ext_vector_type(8)));   // 8 bf16 (4 VGPRs)
typedef float f4  __attribute__((ext_vector_type(4)));   // MFMA acc
typedef unsigned short u16;
typedef unsigned long long u64;

#define LOG2E 1.4426950408889634f

__device__ __forceinline__ u16 f2bf(float f){
  uint32_t u = __builtin_bit_cast(uint32_t, f);
  u += 0x7fffu + ((u >> 16) & 1u);
  return (u16)(u >> 16);
}

// Fused LSTM cell from prescaled pre-activations.
// ai,af,ao prescaled by log2e; ag by 2*log2e; E* = 2^-a*.
// c' = c/(1+Ef) + (1-Eg)/((1+Ei)(1+Eg))   [one rcp via common denominator]
// h  = (1-Ec)/((1+Eo)(1+Ec)),  Ec = 2^(-2*log2e*c')
// 5 exp2 + 2 rcp = 7 trans ops.
__device__ __forceinline__ float lstm_cell(float ai, float af, float ag, float ao, float& c){
  float Ei = __builtin_amdgcn_exp2f(-ai);
  float Ef = __builtin_amdgcn_exp2f(-af);
  float Eg = __builtin_amdgcn_exp2f(-ag);
  float Eo = __builtin_amdgcn_exp2f(-ao);
  float m1  = (1.f + Ei) * (1.f + Eg);
  float a3  = 1.f + Ef;
  float num = fmaf(c, m1, (1.f - Eg) * a3);
  c = num * __builtin_amdgcn_rcpf(a3 * m1);
  float Ec = __builtin_amdgcn_exp2f(c * (-2.f * LOG2E));
  return (1.f - Ec) * __builtin_amdgcn_rcpf((1.f + Eo) * (1.f + Ec));
}

// ---------------------------------------------------------------------------
// Prep: prescaled bf16 weights W0c[512][160]=[Whh0|Wih0|0], W1c[512][256]=
// [Whh1|Wih1]; rows scaled log2e (i,f,o) / 2*log2e (g); prescaled biases;
// zero the progress counters (ws is poisoned 0xAA before every launch!).
// ---------------------------------------------------------------------------
__global__ void prep_kernel(const float* __restrict__ Wih0, const float* __restrict__ Whh0,
                            const float* __restrict__ bih0, const float* __restrict__ bhh0,
                            const float* __restrict__ Wih1, const float* __restrict__ Whh1,
                            const float* __restrict__ bih1, const float* __restrict__ bhh1,
                            u16* __restrict__ W0c, u16* __restrict__ W1c,
                            float* __restrict__ bias0, float* __restrict__ bias1,
                            int* __restrict__ prog){
  int g = blockIdx.x;      // gate row 0..511
  int t = threadIdx.x;     // 0..63
  float s = (g >= 256 && g < 384) ? 2.0f * LOG2E : LOG2E;
  for(int k = t; k < 160; k += 64){
    float v = 0.0f;
    if(k < 128)      v = Whh0[g*128 + k];
    else if(k < 146) v = Wih0[g*18 + (k-128)];
    W0c[g*160 + k] = f2bf(v * s);
  }
  for(int k = t; k < 256; k += 64){
    float v = (k < 128) ? Whh1[g*128 + k] : Wih1[g*128 + (k-128)];
    W1c[g*256 + k] = f2bf(v * s);
  }
  if(t == 0){
    bias0[g] = (bih0[g] + bhh0[g]) * s;
    bias1[g] = (bih1[g] + bhh1[g]) * s;
  }
  if(g == 0 && t < 32) prog[t] = 0;
}

// ---------------------------------------------------------------------------
// Fused 2-layer LSTM. 64 blocks x 512 threads; bid<32: L0 role, else L1.
// R8 = EXACT restoration of the R2 champion (563us). Six structural probes
// (R3-R7: occupancy attrs, skew balance, MFMA split, reg-direct gather, poll
// reorder) were all neutral-to-negative; even instruction reordering within
// the step costs double-digit %. This schedule is the measured local optimum:
//  * __launch_bounds__(512,1), 7-trans fused cell, off-chain pre-MFMA for the
//    known-ahead operand (x / h1), poll+prefetch issued BEFORE the dependent
//    chains (early vmem issue — R7 showed moving it later costs 17%).
// ---------------------------------------------------------------------------
__global__ __launch_bounds__(512, 1)
void lstm_fused(const u16* __restrict__ Wc0, const u16* __restrict__ Wc1,
                const float* __restrict__ bias0, const float* __restrict__ bias1,
                const float* __restrict__ xin,   // (512,512,18) f32
                u64* __restrict__ h1g,           // [T][512 rows][32 u64] bf16x4
                int* __restrict__ prog,          // [32] per-rowblock progress
                const float* __restrict__ Wfc1, const float* __restrict__ bfc1,
                const float* __restrict__ Wfc2, const float* __restrict__ bfc2,
                float* __restrict__ out)         // (512,) f32
{
  __shared__ __align__(16) u16  hb[2][16][136];   // L0 h-state (cols 0..127)
  __shared__ __align__(16) u16  xb[2][16][40];    // L0 x tiles (cols 18..31 stay 0)
  __shared__ __align__(16) u16  h2b[2][16][136];  // L1 h2 state
  __shared__ __align__(16) u16  ring[4][16][136]; // L1 h1 ring
  __shared__ __align__(16) float ffin[16][132];   // final h2 f32 for FC head

  const int tid  = threadIdx.x;
  const int wave = tid >> 6;
  const int lane = tid & 63;
  const int quad = lane >> 4;
  const int l15  = lane & 15;
  const bool isL0 = (blockIdx.x < 32);
  const int rb   = isL0 ? blockIdx.x : (blockIdx.x - 32);
  const int rowbase = rb * 16;

  if(isL0){
    // ------------- L0: h-part K=128 (kt0..3) + x-part K=32 (own tile) -----
    bf8 Ah[4][4], Ax[4];
#pragma unroll
    for(int q = 0; q < 4; q++){
      const u16* wp = Wc0 + (u64)(128*q + 16*wave + l15)*160 + quad*8;
#pragma unroll
      for(int kt = 0; kt < 4; kt++) Ah[q][kt] = *(const bf8*)(wp + kt*32);
      Ax[q] = *(const bf8*)(wp + 128);
    }
    f4 bini[4];
#pragma unroll
    for(int q = 0; q < 4; q++) bini[q] = *(const f4*)(bias0 + 128*q + 16*wave + quad*4);
    float c[4] = {0.f,0.f,0.f,0.f};

    for(int i = tid; i < 2*16*136; i += 512) ((u16*)hb)[i] = 0;
    for(int i = tid; i < 2*16*40;  i += 512) ((u16*)xb)[i] = 0;
    __syncthreads();

    int sr = 0, sk = 0;
    if(tid < 288){
      sr = tid/18; sk = tid - 18*sr;
      xb[0][sr][sk] = f2bf(xin[((u64)(rowbase+sr)*512 + 0)*18 + sk]);
      xb[1][sr][sk] = f2bf(xin[((u64)(rowbase+sr)*512 + 1)*18 + sk]);
    }
    float xv = 0.f;
    if(tid < 288) xv = xin[((u64)(rowbase+sr)*512 + 2)*18 + sk];
    __syncthreads();

    f4 pre[4];
    {
      bf8 Bx = *(const bf8*)(&xb[0][l15][quad*8]);
#pragma unroll
      for(int q = 0; q < 4; q++)
        pre[q] = __builtin_amdgcn_mfma_f32_16x16x32_bf16(Ax[q], Bx, bini[q], 0,0,0);
    }
    __syncthreads();   // xb[0] gets overwritten at t=0

    for(int t = 0; t < 512; t++){
      const int cur = t & 1, nxt = cur ^ 1;
      // stage x(t+2) from reg; issue load of x(t+3) (uniform vmem count)
      if(tid < 288){
        if(t <= 509) xb[t & 1][sr][sk] = f2bf(xv);
        const int tl = (t + 3 < 512) ? t + 3 : 511;
        xv = xin[((u64)(rowbase+sr)*512 + tl)*18 + sk];
      }

      bf8 B[4];
      const u16* br = &hb[cur][l15][quad*8];
#pragma unroll
      for(int kt = 0; kt < 4; kt++) B[kt] = *(const bf8*)(br + kt*32);

      f4 acc[4];
#pragma unroll
      for(int q = 0; q < 4; q++){
        f4 a = pre[q];
#pragma unroll
        for(int kt = 0; kt < 4; kt++)
          a = __builtin_amdgcn_mfma_f32_16x16x32_bf16(Ah[q][kt], B[kt], a, 0,0,0);
        acc[q] = a;
      }

      u64 hpack; u16* hp = (u16*)&hpack;
#pragma unroll
      for(int r = 0; r < 4; r++)
        hp[r] = f2bf(lstm_cell(acc[0][r], acc[1][r], acc[2][r], acc[3][r], c[r]));

      *(u64*)(&hb[nxt][l15][16*wave + quad*4]) = hpack;
      __hip_atomic_store(h1g + ((u64)t*512 + rowbase + l15)*32 + 4*wave + quad,
                         hpack, __ATOMIC_RELAXED, __HIP_MEMORY_SCOPE_AGENT);

      // precompute x-part for step t+1 (off the dependent chain)
      if(t < 511){
        bf8 Bxn = *(const bf8*)(&xb[(t+1) & 1][l15][quad*8]);
#pragma unroll
        for(int q = 0; q < 4; q++)
          pre[q] = __builtin_amdgcn_mfma_f32_16x16x32_bf16(Ax[q], Bxn, bini[q], 0,0,0);
      }

      // counted-vmcnt barrier. Per step, waves 0-4 issue [xload, h1store],
      // waves 5-7 [h1store]. vmcnt(4)/(2) ==> store(t-2) retired (in-order),
      // so publishing prog = t-1 is completion-safe with a relaxed store.
      __builtin_amdgcn_sched_barrier(0);
      if(wave < 5) asm volatile("s_waitcnt vmcnt(4) lgkmcnt(0)" ::: "memory");
      else         asm volatile("s_waitcnt vmcnt(2) lgkmcnt(0)" ::: "memory");
      __builtin_amdgcn_s_barrier();
      __builtin_amdgcn_sched_barrier(0);
      if(tid == 0 && t > 0)
        __hip_atomic_store(prog + rb, t - 1, __ATOMIC_RELAXED, __HIP_MEMORY_SCOPE_AGENT);
    }
    asm volatile("s_waitcnt vmcnt(0)" ::: "memory");
    __builtin_amdgcn_s_barrier();
    if(tid == 0)
      __hip_atomic_store(prog + rb, 512, __ATOMIC_RELAXED, __HIP_MEMORY_SCOPE_AGENT);
  } else {
    // ------------- L1: h2-part K=128 (chain) + h1-part K=128 (pre) --------
    bf8 A2[4][4], A1[4][4];
#pragma unroll
    for(int q = 0; q < 4; q++){
      const u16* wp = Wc1 + (u64)(128*q + 16*wave + l15)*256 + quad*8;
#pragma unroll
      for(int kt = 0; kt < 4; kt++){
        A2[q][kt] = *(const bf8*)(wp + kt*32);
        A1[q][kt] = *(const bf8*)(wp + 128 + kt*32);
      }
    }
    f4 bini[4];
#pragma unroll
    for(int q = 0; q < 4; q++) bini[q] = *(const f4*)(bias1 + 128*q + 16*wave + quad*4);
    float c[4] = {0.f,0.f,0.f,0.f};

    for(int i = tid; i < 2*16*136; i += 512) ((u16*)h2b)[i] = 0;

    const int pr = tid >> 5;          // staging row 0..15
    const int pu = tid & 31;          // staging u64-chunk (4 comps)
    int seen = 0;
    __syncthreads();

    // prologue: stage h1(0)->ring0, h1(1)->ring1; preload pv=h1(2)
    while(seen < 2){
      seen = __hip_atomic_load(prog + rb, __ATOMIC_ACQUIRE, __HIP_MEMORY_SCOPE_AGENT);
      if(seen < 2) __builtin_amdgcn_s_sleep(2);
    }
    {
      u64 v0 = __hip_atomic_load(h1g + ((u64)0*512 + rowbase + pr)*32 + pu,
                                 __ATOMIC_RELAXED, __HIP_MEMORY_SCOPE_AGENT);
      *(u64*)(&ring[0][pr][pu*4]) = v0;
      u64 v1 = __hip_atomic_load(h1g + ((u64)1*512 + rowbase + pr)*32 + pu,
                                 __ATOMIC_RELAXED, __HIP_MEMORY_SCOPE_AGENT);
      *(u64*)(&ring[1][pr][pu*4]) = v1;
    }
    while(seen < 3){
      seen = __hip_atomic_load(prog + rb, __ATOMIC_ACQUIRE, __HIP_MEMORY_SCOPE_AGENT);
      if(seen < 3) __builtin_amdgcn_s_sleep(2);
    }
    u64 pv = __hip_atomic_load(h1g + ((u64)2*512 + rowbase + pr)*32 + pu,
                               __ATOMIC_RELAXED, __HIP_MEMORY_SCOPE_AGENT);
    __syncthreads();

    f4 pre[4];
    {
      const u16* rr = &ring[0][l15][quad*8];
#pragma unroll
      for(int q = 0; q < 4; q++){
        f4 a = bini[q];
#pragma unroll
        for(int kt = 0; kt < 4; kt++)
          a = __builtin_amdgcn_mfma_f32_16x16x32_bf16(A1[q][kt], *(const bf8*)(rr + kt*32), a, 0,0,0);
        pre[q] = a;
      }
    }

    float hv[4] = {0.f,0.f,0.f,0.f};
    for(int t = 0; t < 512; t++){
      const int cur = t & 1, nxt = cur ^ 1;

      bf8 B2[4];
      const u16* br2 = &h2b[cur][l15][quad*8];
#pragma unroll
      for(int kt = 0; kt < 4; kt++) B2[kt] = *(const bf8*)(br2 + kt*32);

      // amortized poll + prefetch h1(t+3)
      u64 pnew = 0;
      if(t <= 508){
        const int need = t + 4;
        while(seen < need){
          seen = __hip_atomic_load(prog + rb, __ATOMIC_ACQUIRE, __HIP_MEMORY_SCOPE_AGENT);
          if(seen < need) __builtin_amdgcn_s_sleep(2);
        }
        pnew = __hip_atomic_load(h1g + ((u64)(t+3)*512 + rowbase + pr)*32 + pu,
                                 __ATOMIC_RELAXED, __HIP_MEMORY_SCOPE_AGENT);
      }

      // 4-deep chain seeded with pre (h1(t) contribution + bias)
      f4 acc[4];
#pragma unroll
      for(int q = 0; q < 4; q++){
        f4 a = pre[q];
#pragma unroll
        for(int kt = 0; kt < 4; kt++)
          a = __builtin_amdgcn_mfma_f32_16x16x32_bf16(A2[q][kt], B2[kt], a, 0,0,0);
        acc[q] = a;
      }

      // precompute h1(t+1) contribution for next step (off-chain)
      if(t < 511){
        const u16* rr = &ring[(t+1) & 3][l15][quad*8];
#pragma unroll
        for(int q = 0; q < 4; q++){
          f4 a = bini[q];
#pragma unroll
          for(int kt = 0; kt < 4; kt++)
            a = __builtin_amdgcn_mfma_f32_16x16x32_bf16(A1[q][kt], *(const bf8*)(rr + kt*32), a, 0,0,0);
          pre[q] = a;
        }
      }

      // stage h1(t+2) (loaded last step) into its ring slot
      if(t <= 509) *(u64*)(&ring[(t+2) & 3][pr][pu*4]) = pv;

      u64 hpack; u16* hp = (u16*)&hpack;
#pragma unroll
      for(int r = 0; r < 4; r++){
        hv[r] = lstm_cell(acc[0][r], acc[1][r], acc[2][r], acc[3][r], c[r]);
        hp[r] = f2bf(hv[r]);
      }
      *(u64*)(&h2b[nxt][l15][16*wave + quad*4]) = hpack;

      __builtin_amdgcn_sched_barrier(0);
      asm volatile("s_waitcnt lgkmcnt(0)" ::: "memory");
      __builtin_amdgcn_s_barrier();
      __builtin_amdgcn_sched_barrier(0);

      pv = pnew;
    }
    // stash final h2 (f32) for FC head
#pragma unroll
    for(int r = 0; r < 4; r++) ffin[l15][16*wave + quad*4 + r] = hv[r];
    __syncthreads();

    // ---- FC head: per row r, 64 hidden, 32 threads x 2v each
    {
      int r = tid >> 5, u = tid & 31;
      float s0 = bfc1[2*u], s1 = bfc1[2*u+1];
      const float* w0 = Wfc1 + (2*u)*128;
      const float* w1 = Wfc1 + (2*u+1)*128;
      for(int j = 0; j < 128; j++){
        float h = ffin[r][j];
        s0 = fmaf(w0[j], h, s0);
        s1 = fmaf(w1[j], h, s1);
      }
      float term = fmaxf(s0, 0.f)*Wfc2[2*u] + fmaxf(s1, 0.f)*Wfc2[2*u+1];
#pragma unroll
      for(int off = 16; off > 0; off >>= 1) term += __shfl_down(term, off, 32);
      if(u == 0){
        float z = (term + bfc2[0]) * LOG2E;
        out[rowbase + r] = __builtin_amdgcn_rcpf(1.0f + __builtin_amdgcn_exp2f(-z));
      }
    }
  }
}

// ---------------------------------------------------------------------------
extern "C" void kernel_launch(void* const* d_in, const int* in_sizes, int n_in,
                              void* d_out, int out_size, void* d_ws, size_t ws_size,
                              hipStream_t stream){
  const float* x    = (const float*)d_in[0];
  const float* Wih0 = (const float*)d_in[1];
  const float* Whh0 = (const float*)d_in[2];
  const float* bih0 = (const float*)d_in[3];
  const float* bhh0 = (const float*)d_in[4];
  const float* Wih1 = (const float*)d_in[5];
  const float* Whh1 = (const float*)d_in[6];
  const float* bih1 = (const float*)d_in[7];
  const float* bhh1 = (const float*)d_in[8];
  const float* Wfc1 = (const float*)d_in[9];
  const float* bfc1 = (const float*)d_in[10];
  const float* Wfc2 = (const float*)d_in[11];
  const float* bfc2 = (const float*)d_in[12];

  char* ws = (char*)d_ws;
  u16*   W0c   = (u16*)(ws);                       // 512*160*2 = 163840 B
  u16*   W1c   = (u16*)(ws + 163840);              // 512*256*2 = 262144 B
  float* bias0 = (float*)(ws + 163840 + 262144);   // 2048 B
  float* bias1 = bias0 + 512;                      // 2048 B
  int*   prog  = (int*)(ws + 163840 + 262144 + 4096);  // 128 B (pad to 256)
  u64*   h1g   = (u64*)(ws + 163840 + 262144 + 4096 + 256); // 64 MiB

  prep_kernel<<<dim3(512), dim3(64), 0, stream>>>(Wih0, Whh0, bih0, bhh0,
                                                  Wih1, Whh1, bih1, bhh1,
                                                  W0c, W1c, bias0, bias1, prog);

  lstm_fused<<<dim3(64), dim3(512), 0, stream>>>(
      W0c, W1c, bias0, bias1, x, h1g, prog,
      Wfc1, bfc1, Wfc2, bfc2, (float*)d_out);
}